// Round 3
// baseline (1278.288 us; speedup 1.0000x reference)
//
#include <hip/hip_runtime.h>
#include <hip/hip_bf16.h>

// EncoderLayer: B=2, S=2048, D_MODEL=512, H=8, D_K=64, D_FF=2048
// Round 3: inputs/outputs are FP32 (reference setup_inputs is jnp.float32;
// rounds 1-2 NaN diagnosed as reading fp32 buffers as bf16 -> random 16-bit
// patterns -> ~1/256 NaN -> every K=512 reduction poisoned).
// Intermediates bf16 (q,k,v,ctx,attn_out,ffmid) / fp32 (x1, ffacc); FFN
// chunked over D_FF in 4 slices. Peak ws = 20 MiB.
// ws layout (MiB):
//   [0,4)   q (bf16)      -> attn_out (bf16) -> ffmid_c (bf16)
//   [4,8)   k (bf16)   --\
//   [8,12)  v (bf16)     +-> x1 (fp32) [4,12)
//   [12,16) ctx (bf16) ----> ffacc (fp32) [12,20)

#define D_MODEL 512
#define N_HEADS 8
#define D_K 64
#define D_FF 2048
#define BATCH 2
#define SEQ 2048
#define NROWS (BATCH * SEQ)

typedef __hip_bfloat16 bf16;

__device__ __forceinline__ float b2f(unsigned short u) {
  return __uint_as_float(((unsigned int)u) << 16);
}
__device__ __forceinline__ unsigned short f2b(float f) {
  union { bf16 b; unsigned short u; } cv;
  cv.b = __float2bfloat16(f);
  return cv.u;
}
__device__ __forceinline__ float toF(const bf16 x) { return __bfloat162float(x); }
__device__ __forceinline__ float toF(const float x) { return x; }

// load 4 consecutive elements as float4
__device__ __forceinline__ float4 load4(const float* p) {
  return *(const float4*)p;
}
__device__ __forceinline__ float4 load4(const bf16* p) {
  const ushort4 u = *(const ushort4*)p;
  return make_float4(b2f(u.x), b2f(u.y), b2f(u.z), b2f(u.w));
}

__device__ __forceinline__ void store4(float* p, float4 v) {
  *(float4*)p = v;
}
__device__ __forceinline__ void store4(bf16* p, float4 v) {
  ushort4 u;
  u.x = f2b(v.x); u.y = f2b(v.y); u.z = f2b(v.z); u.w = f2b(v.w);
  *(ushort4*)p = u;
}

// ---------------------------------------------------------------------------
// Tiled GEMM view: C[M, Ncols] (+)= A[M,K] @ W[K, Ncols] (+ bias, ReLU).
// W has leading dim ldw (>= Ncols view), C leading dim ldc.
// BM=BN=64, BK=16, block=256 (16x16 threads, 4x4 microtile). fp32 accum.
// ACCUM: C += result (bias ignored). Grid: (Ncols/64, M/64).
// ---------------------------------------------------------------------------
template <typename AT, typename CT, bool RELU, bool ACCUM>
__global__ __launch_bounds__(256) void gemm_kernel(
    const AT* __restrict__ A, const float* __restrict__ W,
    const float* __restrict__ bias, CT* __restrict__ C,
    int M, int K, int ldw, int ldc) {
  __shared__ float As[16][68];
  __shared__ float Bs[16][68];

  const int rowBase = blockIdx.y * 64;
  const int colBase = blockIdx.x * 64;
  const int t = threadIdx.x;
  const int tx = t & 15;
  const int ty = t >> 4;

  float acc[4][4];
#pragma unroll
  for (int i = 0; i < 4; ++i)
#pragma unroll
    for (int j = 0; j < 4; ++j) acc[i][j] = 0.f;

  const int ar = t >> 2;        // 0..63 : A row within tile
  const int akc = (t & 3) * 4;  // 0,4,8,12 : A k-offset
  const int wc = t & 63;        // 0..63 : W col within tile
  const int wkr = t >> 6;       // 0..3 : W k base

  for (int k0 = 0; k0 < K; k0 += 16) {
    {
      const float4 a4 = load4(&A[(size_t)(rowBase + ar) * K + k0 + akc]);
      As[akc + 0][ar] = a4.x;
      As[akc + 1][ar] = a4.y;
      As[akc + 2][ar] = a4.z;
      As[akc + 3][ar] = a4.w;
    }
#pragma unroll
    for (int j = 0; j < 4; ++j)
      Bs[wkr + 4 * j][wc] = W[(size_t)(k0 + wkr + 4 * j) * ldw + colBase + wc];
    __syncthreads();

#pragma unroll
    for (int kk = 0; kk < 16; ++kk) {
      float4 a4 = *(const float4*)&As[kk][ty * 4];
      float4 b4 = *(const float4*)&Bs[kk][tx * 4];
      float a[4] = {a4.x, a4.y, a4.z, a4.w};
      float b[4] = {b4.x, b4.y, b4.z, b4.w};
#pragma unroll
      for (int i = 0; i < 4; ++i)
#pragma unroll
        for (int j = 0; j < 4; ++j) acc[i][j] += a[i] * b[j];
    }
    __syncthreads();
  }

#pragma unroll
  for (int i = 0; i < 4; ++i) {
    const int r = rowBase + ty * 4 + i;
    CT* cp = &C[(size_t)r * ldc + colBase + tx * 4];
    float4 o;
    float* op = &o.x;
#pragma unroll
    for (int j = 0; j < 4; ++j) {
      float v = acc[i][j];
      if (!ACCUM) v += bias[colBase + tx * 4 + j];
      if (RELU) v = fmaxf(v, 0.f);
      op[j] = v;
    }
    if (ACCUM) {
      const float4 old = load4(cp);
      o.x += old.x; o.y += old.y; o.z += old.z; o.w += old.w;
    }
    store4(cp, o);
  }
}

// ---------------------------------------------------------------------------
// Flash-style attention: grid (SEQ/16, B*H), block 256. Q,K,V bf16
// [B*S, D_MODEL] (head h in cols h*64..h*64+63). Online softmax over
// 64-key tiles, fp32 internal; ctx written bf16.
// ---------------------------------------------------------------------------
__global__ __launch_bounds__(256) void attn_kernel(
    const bf16* __restrict__ Q, const bf16* __restrict__ Km,
    const bf16* __restrict__ V, const int* __restrict__ mask,
    bf16* __restrict__ ctx) {
  const int qt = blockIdx.x;
  const int bh = blockIdx.y;
  const int b = bh / N_HEADS;
  const int h = bh % N_HEADS;
  const int t = threadIdx.x;
  const int q0 = qt * 16;

  __shared__ float qs[16][68];
  __shared__ float ks[64][68];
  __shared__ float vs[64][68];
  __shared__ float st[16][64];
  __shared__ float osh[16][68];
  __shared__ float red[16][16];
  __shared__ float m_run[16], l_run[16], row_mnew[16], row_alpha[16];
  __shared__ int mk[64];

  const int qi = t >> 4;   // 0..15
  const int sub = t & 15;  // 0..15
  const int k0q = sub * 4; // key group for scores
  const int d0 = sub * 4;  // dim group for q load / o update

  {
    float4 qv = load4(&Q[(size_t)(b * SEQ + q0 + qi) * D_MODEL + h * D_K + d0]);
    qs[qi][d0 + 0] = qv.x * 0.125f;  // 1/sqrt(D_K)
    qs[qi][d0 + 1] = qv.y * 0.125f;
    qs[qi][d0 + 2] = qv.z * 0.125f;
    qs[qi][d0 + 3] = qv.w * 0.125f;
    *(float4*)&osh[qi][d0] = make_float4(0.f, 0.f, 0.f, 0.f);
    if (t < 16) { m_run[t] = -1e30f; l_run[t] = 0.f; }
  }
  __syncthreads();

  for (int kt = 0; kt < SEQ / 64; ++kt) {
    {  // stage K/V tile (64x64 each) + mask
      const int r = t >> 2;
      const int c0 = (t & 3) * 16;
      const bf16* ksrc = &Km[(size_t)(b * SEQ + kt * 64 + r) * D_MODEL + h * D_K + c0];
      const bf16* vsrc = &V[(size_t)(b * SEQ + kt * 64 + r) * D_MODEL + h * D_K + c0];
#pragma unroll
      for (int j = 0; j < 16; j += 4) {
        *(float4*)&ks[r][c0 + j] = load4(&ksrc[j]);
        *(float4*)&vs[r][c0 + j] = load4(&vsrc[j]);
      }
      if (t < 64) mk[t] = mask[b * SEQ + kt * 64 + t];
    }
    __syncthreads();

    // scores for (qi, keys k0q..k0q+3)
    float sc[4] = {0.f, 0.f, 0.f, 0.f};
    for (int j = 0; j < 64; j += 4) {
      float4 q4 = *(const float4*)&qs[qi][j];
#pragma unroll
      for (int kk = 0; kk < 4; ++kk) {
        float4 k4 = *(const float4*)&ks[k0q + kk][j];
        sc[kk] += q4.x * k4.x + q4.y * k4.y + q4.z * k4.z + q4.w * k4.w;
      }
    }
    float pm = -1e30f;
#pragma unroll
    for (int kk = 0; kk < 4; ++kk) {
      if (mk[k0q + kk] == 0) sc[kk] = -1e9f;
      pm = fmaxf(pm, sc[kk]);
    }
    red[qi][sub] = pm;
    __syncthreads();

    if (t < 16) {
      float mm = m_run[t];
#pragma unroll
      for (int i2 = 0; i2 < 16; ++i2) mm = fmaxf(mm, red[t][i2]);
      row_mnew[t] = mm;
    }
    __syncthreads();

    const float mnew = row_mnew[qi];
    float ps = 0.f;
#pragma unroll
    for (int kk = 0; kk < 4; ++kk) {
      float p = __expf(sc[kk] - mnew);
      st[qi][k0q + kk] = p;
      ps += p;
    }
    red[qi][sub] = ps;
    __syncthreads();

    if (t < 16) {
      float s = 0.f;
#pragma unroll
      for (int i2 = 0; i2 < 16; ++i2) s += red[t][i2];
      const float alpha = __expf(m_run[t] - row_mnew[t]);
      l_run[t] = l_run[t] * alpha + s;
      m_run[t] = row_mnew[t];
      row_alpha[t] = alpha;
    }
    __syncthreads();

    // o update: thread handles (qi, dims d0..d0+3)
    const float alpha = row_alpha[qi];
    float4 o4 = *(float4*)&osh[qi][d0];
    o4.x *= alpha; o4.y *= alpha; o4.z *= alpha; o4.w *= alpha;
    for (int k = 0; k < 64; ++k) {
      const float p = st[qi][k];
      const float4 v4 = *(const float4*)&vs[k][d0];
      o4.x += p * v4.x; o4.y += p * v4.y; o4.z += p * v4.z; o4.w += p * v4.w;
    }
    *(float4*)&osh[qi][d0] = o4;
    __syncthreads();
  }

  const float inv_l = 1.f / l_run[qi];
  ushort4 o;
  o.x = f2b(osh[qi][d0 + 0] * inv_l);
  o.y = f2b(osh[qi][d0 + 1] * inv_l);
  o.z = f2b(osh[qi][d0 + 2] * inv_l);
  o.w = f2b(osh[qi][d0 + 3] * inv_l);
  *(ushort4*)&ctx[(size_t)(b * SEQ + q0 + qi) * D_MODEL + h * D_K + d0] = o;
}

// ---------------------------------------------------------------------------
// Fused residual + LayerNorm over rows of 512. grid = NROWS, block = 256.
// out = LN(base + res) * g + beta   (fp32 math)
// ---------------------------------------------------------------------------
template <typename BT, typename RT, typename OT>
__global__ __launch_bounds__(256) void ln_kernel(
    const BT* __restrict__ base, const RT* __restrict__ res,
    const float* __restrict__ g, const float* __restrict__ beta,
    OT* __restrict__ out) {
  const int r = blockIdx.x;
  const int t = threadIdx.x;
  __shared__ float sred[256];

  const size_t rb = (size_t)r * D_MODEL;
  float v0 = toF(base[rb + t]) + toF(res[rb + t]);
  float v1 = toF(base[rb + t + 256]) + toF(res[rb + t + 256]);

  sred[t] = v0 + v1;
  __syncthreads();
#pragma unroll
  for (int s2 = 128; s2 > 0; s2 >>= 1) {
    if (t < s2) sred[t] += sred[t + s2];
    __syncthreads();
  }
  const float mu = sred[0] * (1.f / (float)D_MODEL);
  __syncthreads();

  const float d0 = v0 - mu;
  const float d1 = v1 - mu;
  sred[t] = d0 * d0 + d1 * d1;
  __syncthreads();
#pragma unroll
  for (int s2 = 128; s2 > 0; s2 >>= 1) {
    if (t < s2) sred[t] += sred[t + s2];
    __syncthreads();
  }
  const float var = sred[0] * (1.f / (float)D_MODEL);
  const float rs = rsqrtf(var + 1e-5f);

  out[rb + t] = (OT)(d0 * rs * g[t] + beta[t]);
  out[rb + t + 256] = (OT)(d1 * rs * g[t + 256] + beta[t + 256]);
}

// ---------------------------------------------------------------------------
extern "C" void kernel_launch(void* const* d_in, const int* in_sizes, int n_in,
                              void* d_out, int out_size, void* d_ws, size_t ws_size,
                              hipStream_t stream) {
  const float* x     = (const float*)d_in[0];
  const int*   mask  = (const int*)d_in[1];
  const float* Wq    = (const float*)d_in[2];
  const float* bq    = (const float*)d_in[3];
  const float* Wk    = (const float*)d_in[4];
  const float* bk    = (const float*)d_in[5];
  const float* Wv    = (const float*)d_in[6];
  const float* bv    = (const float*)d_in[7];
  const float* Wo    = (const float*)d_in[8];
  const float* bo    = (const float*)d_in[9];
  const float* W1    = (const float*)d_in[10];
  const float* b1    = (const float*)d_in[11];
  const float* W2    = (const float*)d_in[12];
  const float* b2    = (const float*)d_in[13];
  const float* g1    = (const float*)d_in[14];
  const float* beta1 = (const float*)d_in[15];
  const float* g2    = (const float*)d_in[16];
  const float* beta2 = (const float*)d_in[17];
  float* out = (float*)d_out;

  char* ws = (char*)d_ws;
  const size_t MB4 = (size_t)NROWS * D_MODEL * sizeof(bf16);  // 4 MiB
  bf16*  q        = (bf16*)(ws + 0 * MB4);
  bf16*  kbuf     = (bf16*)(ws + 1 * MB4);
  bf16*  vbuf     = (bf16*)(ws + 2 * MB4);
  bf16*  ctx      = (bf16*)(ws + 3 * MB4);
  bf16*  attn_out = q;                        // q dead after attention
  float* x1       = (float*)(ws + 1 * MB4);   // [4,12) k,v dead after attn
  bf16*  ffmid    = (bf16*)(ws + 0 * MB4);    // [0,4) attn_out dead after ln1
  float* ffacc    = (float*)(ws + 3 * MB4);   // [12,20) ctx dead after Wo

  const dim3 blk(256);

  // QKV projections (fp32 x @ fp32 W -> bf16)
  gemm_kernel<float, bf16, false, false>
      <<<dim3(D_MODEL / 64, NROWS / 64), blk, 0, stream>>>(
          x, Wq, bq, q, NROWS, D_MODEL, D_MODEL, D_MODEL);
  gemm_kernel<float, bf16, false, false>
      <<<dim3(D_MODEL / 64, NROWS / 64), blk, 0, stream>>>(
          x, Wk, bk, kbuf, NROWS, D_MODEL, D_MODEL, D_MODEL);
  gemm_kernel<float, bf16, false, false>
      <<<dim3(D_MODEL / 64, NROWS / 64), blk, 0, stream>>>(
          x, Wv, bv, vbuf, NROWS, D_MODEL, D_MODEL, D_MODEL);

  // attention
  attn_kernel<<<dim3(SEQ / 16, BATCH * N_HEADS), blk, 0, stream>>>(
      q, kbuf, vbuf, mask, ctx);

  // output projection (bf16 ctx @ fp32 Wo -> bf16)
  gemm_kernel<bf16, bf16, false, false>
      <<<dim3(D_MODEL / 64, NROWS / 64), blk, 0, stream>>>(
          ctx, Wo, bo, attn_out, NROWS, D_MODEL, D_MODEL, D_MODEL);

  // LN1: x1 = LN(x + attn_out) (fp32 out)
  ln_kernel<float, bf16, float><<<NROWS, blk, 0, stream>>>(
      x, attn_out, g1, beta1, x1);

  // FFN, chunked over D_FF in 4 slices of 512
  for (int c = 0; c < 4; ++c) {
    // ffmid = relu(x1 @ W1[:, c*512:(c+1)*512] + b1[c*512:])  (bf16)
    gemm_kernel<float, bf16, true, false>
        <<<dim3(512 / 64, NROWS / 64), blk, 0, stream>>>(
            x1, W1 + c * 512, b1 + c * 512, ffmid, NROWS, D_MODEL, D_FF, 512);
    // ffacc (+)= ffmid @ W2[c*512:(c+1)*512, :] (+ b2 on first chunk)
    if (c == 0)
      gemm_kernel<bf16, float, false, false>
          <<<dim3(D_MODEL / 64, NROWS / 64), blk, 0, stream>>>(
              ffmid, W2 + (size_t)c * 512 * D_MODEL, b2, ffacc,
              NROWS, 512, D_MODEL, D_MODEL);
    else
      gemm_kernel<bf16, float, false, true>
          <<<dim3(D_MODEL / 64, NROWS / 64), blk, 0, stream>>>(
              ffmid, W2 + (size_t)c * 512 * D_MODEL, b2, ffacc,
              NROWS, 512, D_MODEL, D_MODEL);
  }

  // LN2 -> fp32 output
  ln_kernel<float, float, float><<<NROWS, blk, 0, stream>>>(
      x1, ffacc, g2, beta2, out);
}

// Round 4
// 615.933 us; speedup vs baseline: 2.0754x; 2.0754x over previous
//
#include <hip/hip_runtime.h>
#include <hip/hip_bf16.h>

// EncoderLayer: B=2, S=2048, D_MODEL=512, H=8, D_K=64, D_FF=2048
// Round 4: MFMA flash attention (attn was 833us/65% of total, 8-way LDS bank
// conflicts + scalar VALU). Block=256 (4 waves), 64 q-rows/block per (b,h);
// Q in registers as A-frags; K row-major LDS [64][72]; V transposed LDS
// vt[d][key] so PV B-frags are contiguous ds_read_b128; online softmax via
// shfl_xor butterflies; P via per-wave LDS round-trip (C-layout -> A-layout).
// GEMMs / LNs unchanged from round 3 (fp32 vector; next round's target).
// ws layout (MiB): [0,4) q->attn_out->ffmid  [4,8) k -\
//                  [8,12) v -> x1[4,12)  [12,16) ctx -> ffacc[12,20)

#define D_MODEL 512
#define N_HEADS 8
#define D_K 64
#define D_FF 2048
#define BATCH 2
#define SEQ 2048
#define NROWS (BATCH * SEQ)

typedef __hip_bfloat16 bf16;
typedef __attribute__((ext_vector_type(8))) short bf16x8;
typedef __attribute__((ext_vector_type(4))) float f32x4;

__device__ __forceinline__ float b2f(unsigned short u) {
  return __uint_as_float(((unsigned int)u) << 16);
}
__device__ __forceinline__ unsigned short f2b(float f) {
  union { bf16 b; unsigned short u; } cv;
  cv.b = __float2bfloat16(f);
  return cv.u;
}
__device__ __forceinline__ float toF(const bf16 x) { return __bfloat162float(x); }
__device__ __forceinline__ float toF(const float x) { return x; }

__device__ __forceinline__ float4 load4(const float* p) { return *(const float4*)p; }
__device__ __forceinline__ float4 load4(const bf16* p) {
  const ushort4 u = *(const ushort4*)p;
  return make_float4(b2f(u.x), b2f(u.y), b2f(u.z), b2f(u.w));
}
__device__ __forceinline__ void store4(float* p, float4 v) { *(float4*)p = v; }
__device__ __forceinline__ void store4(bf16* p, float4 v) {
  ushort4 u;
  u.x = f2b(v.x); u.y = f2b(v.y); u.z = f2b(v.z); u.w = f2b(v.w);
  *(ushort4*)p = u;
}

// ---------------------------------------------------------------------------
// Tiled GEMM view: C[M, Ncols] (+)= A[M,K] @ W[K, Ncols] (+ bias, ReLU).
// BM=BN=64, BK=16, block=256, 4x4 microtile. fp32 accum. (unchanged r3)
// ---------------------------------------------------------------------------
template <typename AT, typename CT, bool RELU, bool ACCUM>
__global__ __launch_bounds__(256) void gemm_kernel(
    const AT* __restrict__ A, const float* __restrict__ W,
    const float* __restrict__ bias, CT* __restrict__ C,
    int M, int K, int ldw, int ldc) {
  __shared__ float As[16][68];
  __shared__ float Bs[16][68];

  const int rowBase = blockIdx.y * 64;
  const int colBase = blockIdx.x * 64;
  const int t = threadIdx.x;
  const int tx = t & 15;
  const int ty = t >> 4;

  float acc[4][4];
#pragma unroll
  for (int i = 0; i < 4; ++i)
#pragma unroll
    for (int j = 0; j < 4; ++j) acc[i][j] = 0.f;

  const int ar = t >> 2;
  const int akc = (t & 3) * 4;
  const int wc = t & 63;
  const int wkr = t >> 6;

  for (int k0 = 0; k0 < K; k0 += 16) {
    {
      const float4 a4 = load4(&A[(size_t)(rowBase + ar) * K + k0 + akc]);
      As[akc + 0][ar] = a4.x;
      As[akc + 1][ar] = a4.y;
      As[akc + 2][ar] = a4.z;
      As[akc + 3][ar] = a4.w;
    }
#pragma unroll
    for (int j = 0; j < 4; ++j)
      Bs[wkr + 4 * j][wc] = W[(size_t)(k0 + wkr + 4 * j) * ldw + colBase + wc];
    __syncthreads();

#pragma unroll
    for (int kk = 0; kk < 16; ++kk) {
      float4 a4 = *(const float4*)&As[kk][ty * 4];
      float4 b4 = *(const float4*)&Bs[kk][tx * 4];
      float a[4] = {a4.x, a4.y, a4.z, a4.w};
      float b[4] = {b4.x, b4.y, b4.z, b4.w};
#pragma unroll
      for (int i = 0; i < 4; ++i)
#pragma unroll
        for (int j = 0; j < 4; ++j) acc[i][j] += a[i] * b[j];
    }
    __syncthreads();
  }

#pragma unroll
  for (int i = 0; i < 4; ++i) {
    const int r = rowBase + ty * 4 + i;
    CT* cp = &C[(size_t)r * ldc + colBase + tx * 4];
    float4 o;
    float* op = &o.x;
#pragma unroll
    for (int j = 0; j < 4; ++j) {
      float v = acc[i][j];
      if (!ACCUM) v += bias[colBase + tx * 4 + j];
      if (RELU) v = fmaxf(v, 0.f);
      op[j] = v;
    }
    if (ACCUM) {
      const float4 old = load4(cp);
      o.x += old.x; o.y += old.y; o.z += old.z; o.w += old.w;
    }
    store4(cp, o);
  }
}

// ---------------------------------------------------------------------------
// MFMA flash attention. grid (SEQ/64, B*H), block 256 (4 waves).
// Wave w handles q-rows [qt*64 + w*16, +16). Q,K,V bf16 [B*S, 512] (head h at
// cols h*64..h*64+63). mfma_f32_16x16x32_bf16 layouts (guide-verified):
//   A: a[j] = A[m=lane&15][k=quad*8+j];  B: b[j] = B[k=quad*8+j][n=lane&15]
//   C/D: d[r] = D[row=quad*4+r][col=lane&15]
// ---------------------------------------------------------------------------
__global__ __launch_bounds__(256) void attn_mfma_kernel(
    const bf16* __restrict__ Q, const bf16* __restrict__ Km,
    const bf16* __restrict__ V, const int* __restrict__ mask,
    bf16* __restrict__ ctx) {
  const int qt = blockIdx.x;
  const int bh = blockIdx.y;
  const int b = bh >> 3;
  const int h = bh & 7;
  const int t = threadIdx.x;
  const int wave = t >> 6;
  const int lane = t & 63;
  const int quad = lane >> 4;
  const int l15 = lane & 15;

  __shared__ short ks[64][72];      // K tile row-major [key][d], pad 72
  __shared__ short vt[64][72];      // V tile transposed [d][key], pad 72
  __shared__ float st[4][16][68];   // per-wave P (fp32, C-layout rows q)
  __shared__ int mk[64];

  // Q A-frags, resident all kernel: k-chunks kc=0 (d 0..31), kc=1 (d 32..63)
  bf16x8 qf[2];
  {
    const short* qg = (const short*)Q +
        (size_t)(b * SEQ + qt * 64 + wave * 16 + l15) * D_MODEL + h * D_K + quad * 8;
    qf[0] = *(const bf16x8*)qg;
    qf[1] = *(const bf16x8*)(qg + 32);
  }

  f32x4 of[4];
#pragma unroll
  for (int nt = 0; nt < 4; ++nt) of[nt] = (f32x4){0.f, 0.f, 0.f, 0.f};
  float m_run[4] = {-1e30f, -1e30f, -1e30f, -1e30f};
  float l_run[4] = {0.f, 0.f, 0.f, 0.f};

  // staging indices
  const int kr = t >> 2, kc0 = (t & 3) * 16;   // K: row, 16-col chunk
  const int vk = t & 63, vc0 = (t >> 6) * 16;  // V: key, 16-d chunk

  for (int kt = 0; kt < SEQ / 64; ++kt) {
    {
      const short* kg = (const short*)Km +
          (size_t)(b * SEQ + kt * 64 + kr) * D_MODEL + h * D_K + kc0;
      *(bf16x8*)&ks[kr][kc0] = *(const bf16x8*)kg;
      *(bf16x8*)&ks[kr][kc0 + 8] = *(const bf16x8*)(kg + 8);
      const short* vg = (const short*)V +
          (size_t)(b * SEQ + kt * 64 + vk) * D_MODEL + h * D_K + vc0;
      bf16x8 v0 = *(const bf16x8*)vg;
      bf16x8 v1 = *(const bf16x8*)(vg + 8);
#pragma unroll
      for (int i = 0; i < 8; ++i) vt[vc0 + i][vk] = v0[i];
#pragma unroll
      for (int i = 0; i < 8; ++i) vt[vc0 + 8 + i][vk] = v1[i];
      if (t < 64) mk[t] = mask[b * SEQ + kt * 64 + t];
    }
    __syncthreads();

    // S = Q @ K^T  (16q x 64k per wave, 4 n-tiles x 2 k-chunks)
    f32x4 sf[4];
#pragma unroll
    for (int nt = 0; nt < 4; ++nt) {
      f32x4 acc = (f32x4){0.f, 0.f, 0.f, 0.f};
      bf16x8 kf0 = *(const bf16x8*)&ks[l15 + 16 * nt][quad * 8];
      bf16x8 kf1 = *(const bf16x8*)&ks[l15 + 16 * nt][quad * 8 + 32];
      acc = __builtin_amdgcn_mfma_f32_16x16x32_bf16(qf[0], kf0, acc, 0, 0, 0);
      acc = __builtin_amdgcn_mfma_f32_16x16x32_bf16(qf[1], kf1, acc, 0, 0, 0);
      sf[nt] = acc;
    }

    // scale + mask + online softmax (rows = quad*4+r, 16 lanes share a row set)
    float mnew[4];
#pragma unroll
    for (int r = 0; r < 4; ++r) mnew[r] = m_run[r];
#pragma unroll
    for (int nt = 0; nt < 4; ++nt) {
      const bool dead = (mk[l15 + 16 * nt] == 0);
#pragma unroll
      for (int r = 0; r < 4; ++r) {
        float s = sf[nt][r] * 0.125f;  // 1/sqrt(D_K)
        if (dead) s = -1e9f;
        sf[nt][r] = s;
        mnew[r] = fmaxf(mnew[r], s);
      }
    }
#pragma unroll
    for (int xm = 1; xm < 16; xm <<= 1)
#pragma unroll
      for (int r = 0; r < 4; ++r)
        mnew[r] = fmaxf(mnew[r], __shfl_xor(mnew[r], xm, 64));

    float lsum[4] = {0.f, 0.f, 0.f, 0.f};
#pragma unroll
    for (int nt = 0; nt < 4; ++nt)
#pragma unroll
      for (int r = 0; r < 4; ++r) {
        float p = __expf(sf[nt][r] - mnew[r]);
        sf[nt][r] = p;
        lsum[r] += p;
      }
#pragma unroll
    for (int xm = 1; xm < 16; xm <<= 1)
#pragma unroll
      for (int r = 0; r < 4; ++r) lsum[r] += __shfl_xor(lsum[r], xm, 64);

#pragma unroll
    for (int r = 0; r < 4; ++r) {
      const float alpha = __expf(m_run[r] - mnew[r]);
      l_run[r] = l_run[r] * alpha + lsum[r];
      m_run[r] = mnew[r];
#pragma unroll
      for (int nt = 0; nt < 4; ++nt) of[nt][r] *= alpha;
    }

    // P: C-layout -> LDS -> A-layout (per-wave buffer, same-wave round trip)
#pragma unroll
    for (int nt = 0; nt < 4; ++nt)
#pragma unroll
      for (int r = 0; r < 4; ++r)
        st[wave][quad * 4 + r][l15 + 16 * nt] = sf[nt][r];

    // O += P @ V
#pragma unroll
    for (int kc = 0; kc < 2; ++kc) {
      float4 p0 = *(const float4*)&st[wave][l15][kc * 32 + quad * 8];
      float4 p1 = *(const float4*)&st[wave][l15][kc * 32 + quad * 8 + 4];
      bf16x8 pf;
      pf[0] = (short)f2b(p0.x); pf[1] = (short)f2b(p0.y);
      pf[2] = (short)f2b(p0.z); pf[3] = (short)f2b(p0.w);
      pf[4] = (short)f2b(p1.x); pf[5] = (short)f2b(p1.y);
      pf[6] = (short)f2b(p1.z); pf[7] = (short)f2b(p1.w);
#pragma unroll
      for (int nt = 0; nt < 4; ++nt) {
        bf16x8 vf = *(const bf16x8*)&vt[l15 + 16 * nt][kc * 32 + quad * 8];
        of[nt] = __builtin_amdgcn_mfma_f32_16x16x32_bf16(pf, vf, of[nt], 0, 0, 0);
      }
    }
    __syncthreads();
  }

  // epilogue: O / l, write ctx (C-layout scatter)
#pragma unroll
  for (int r = 0; r < 4; ++r) {
    const float inv_l = 1.f / l_run[r];
    const int row = qt * 64 + wave * 16 + quad * 4 + r;
    bf16* cp = ctx + (size_t)(b * SEQ + row) * D_MODEL + h * D_K;
#pragma unroll
    for (int nt = 0; nt < 4; ++nt)
      cp[l15 + 16 * nt] = __float2bfloat16(of[nt][r] * inv_l);
  }
}

// ---------------------------------------------------------------------------
// Fused residual + LayerNorm over rows of 512. grid = NROWS, block = 256.
// ---------------------------------------------------------------------------
template <typename BT, typename RT, typename OT>
__global__ __launch_bounds__(256) void ln_kernel(
    const BT* __restrict__ base, const RT* __restrict__ res,
    const float* __restrict__ g, const float* __restrict__ beta,
    OT* __restrict__ out) {
  const int r = blockIdx.x;
  const int t = threadIdx.x;
  __shared__ float sred[256];

  const size_t rb = (size_t)r * D_MODEL;
  float v0 = toF(base[rb + t]) + toF(res[rb + t]);
  float v1 = toF(base[rb + t + 256]) + toF(res[rb + t + 256]);

  sred[t] = v0 + v1;
  __syncthreads();
#pragma unroll
  for (int s2 = 128; s2 > 0; s2 >>= 1) {
    if (t < s2) sred[t] += sred[t + s2];
    __syncthreads();
  }
  const float mu = sred[0] * (1.f / (float)D_MODEL);
  __syncthreads();

  const float d0 = v0 - mu;
  const float d1 = v1 - mu;
  sred[t] = d0 * d0 + d1 * d1;
  __syncthreads();
#pragma unroll
  for (int s2 = 128; s2 > 0; s2 >>= 1) {
    if (t < s2) sred[t] += sred[t + s2];
    __syncthreads();
  }
  const float var = sred[0] * (1.f / (float)D_MODEL);
  const float rs = rsqrtf(var + 1e-5f);

  out[rb + t] = (OT)(d0 * rs * g[t] + beta[t]);
  out[rb + t + 256] = (OT)(d1 * rs * g[t + 256] + beta[t + 256]);
}

// ---------------------------------------------------------------------------
extern "C" void kernel_launch(void* const* d_in, const int* in_sizes, int n_in,
                              void* d_out, int out_size, void* d_ws, size_t ws_size,
                              hipStream_t stream) {
  const float* x     = (const float*)d_in[0];
  const int*   mask  = (const int*)d_in[1];
  const float* Wq    = (const float*)d_in[2];
  const float* bq    = (const float*)d_in[3];
  const float* Wk    = (const float*)d_in[4];
  const float* bk    = (const float*)d_in[5];
  const float* Wv    = (const float*)d_in[6];
  const float* bv    = (const float*)d_in[7];
  const float* Wo    = (const float*)d_in[8];
  const float* bo    = (const float*)d_in[9];
  const float* W1    = (const float*)d_in[10];
  const float* b1    = (const float*)d_in[11];
  const float* W2    = (const float*)d_in[12];
  const float* b2    = (const float*)d_in[13];
  const float* g1    = (const float*)d_in[14];
  const float* beta1 = (const float*)d_in[15];
  const float* g2    = (const float*)d_in[16];
  const float* beta2 = (const float*)d_in[17];
  float* out = (float*)d_out;

  char* ws = (char*)d_ws;
  const size_t MB4 = (size_t)NROWS * D_MODEL * sizeof(bf16);  // 4 MiB
  bf16*  q        = (bf16*)(ws + 0 * MB4);
  bf16*  kbuf     = (bf16*)(ws + 1 * MB4);
  bf16*  vbuf     = (bf16*)(ws + 2 * MB4);
  bf16*  ctx      = (bf16*)(ws + 3 * MB4);
  bf16*  attn_out = q;
  float* x1       = (float*)(ws + 1 * MB4);   // [4,12)
  bf16*  ffmid    = (bf16*)(ws + 0 * MB4);    // [0,4)
  float* ffacc    = (float*)(ws + 3 * MB4);   // [12,20)

  const dim3 blk(256);

  gemm_kernel<float, bf16, false, false>
      <<<dim3(D_MODEL / 64, NROWS / 64), blk, 0, stream>>>(
          x, Wq, bq, q, NROWS, D_MODEL, D_MODEL, D_MODEL);
  gemm_kernel<float, bf16, false, false>
      <<<dim3(D_MODEL / 64, NROWS / 64), blk, 0, stream>>>(
          x, Wk, bk, kbuf, NROWS, D_MODEL, D_MODEL, D_MODEL);
  gemm_kernel<float, bf16, false, false>
      <<<dim3(D_MODEL / 64, NROWS / 64), blk, 0, stream>>>(
          x, Wv, bv, vbuf, NROWS, D_MODEL, D_MODEL, D_MODEL);

  attn_mfma_kernel<<<dim3(SEQ / 64, BATCH * N_HEADS), blk, 0, stream>>>(
      q, kbuf, vbuf, mask, ctx);

  gemm_kernel<bf16, bf16, false, false>
      <<<dim3(D_MODEL / 64, NROWS / 64), blk, 0, stream>>>(
          ctx, Wo, bo, attn_out, NROWS, D_MODEL, D_MODEL, D_MODEL);

  ln_kernel<float, bf16, float><<<NROWS, blk, 0, stream>>>(
      x, attn_out, g1, beta1, x1);

  for (int c = 0; c < 4; ++c) {
    gemm_kernel<float, bf16, true, false>
        <<<dim3(512 / 64, NROWS / 64), blk, 0, stream>>>(
            x1, W1 + c * 512, b1 + c * 512, ffmid, NROWS, D_MODEL, D_FF, 512);
    if (c == 0)
      gemm_kernel<bf16, float, false, false>
          <<<dim3(D_MODEL / 64, NROWS / 64), blk, 0, stream>>>(
              ffmid, W2 + (size_t)c * 512 * D_MODEL, b2, ffacc,
              NROWS, 512, D_MODEL, D_MODEL);
    else
      gemm_kernel<bf16, float, false, true>
          <<<dim3(D_MODEL / 64, NROWS / 64), blk, 0, stream>>>(
              ffmid, W2 + (size_t)c * 512 * D_MODEL, b2, ffacc,
              NROWS, 512, D_MODEL, D_MODEL);
  }

  ln_kernel<float, float, float><<<NROWS, blk, 0, stream>>>(
      x1, ffacc, g2, beta2, out);
}

// Round 5
// 310.400 us; speedup vs baseline: 4.1182x; 1.9843x over previous
//
#include <hip/hip_runtime.h>
#include <hip/hip_bf16.h>

// EncoderLayer: B=2, S=2048, D_MODEL=512, H=8, D_K=64, D_FF=2048
// Round 5: all GEMMs -> bf16 MFMA (they were 520us/85% at MfmaUtil=0).
// gemm_mfma: BM=64,BN=64,BK=32, block=256 (4 waves, wave=16 rows x 64 cols),
// A and W staged to LDS bf16 [row][40] (80B rows: 16B aligned, bank-even),
// all frag accesses ds_read_b128; W transpose-staged with coalesced loads.
// QKV fused via blockIdx.z. FFN 2 chunks of 1024 (ffmid 8MiB); ffacc bf16.
// Attention kernel unchanged from round 4 (95us, MfmaUtil 7%).
// ws (MiB): q[0,4) k[4,8) v[8,12) ctx[12,16); attn_out=q; x1(bf16)=[4,8);
//           ffmid[8,16); ffacc(bf16)[16,20).  Peak 20 MiB.

#define D_MODEL 512
#define N_HEADS 8
#define D_K 64
#define D_FF 2048
#define BATCH 2
#define SEQ 2048
#define NROWS (BATCH * SEQ)

typedef __hip_bfloat16 bf16;
typedef __attribute__((ext_vector_type(8))) short bf16x8;
typedef __attribute__((ext_vector_type(4))) float f32x4;

__device__ __forceinline__ float b2f(unsigned short u) {
  return __uint_as_float(((unsigned int)u) << 16);
}
__device__ __forceinline__ unsigned short f2b(float f) {
  union { bf16 b; unsigned short u; } cv;
  cv.b = __float2bfloat16(f);
  return cv.u;
}
__device__ __forceinline__ float toF(const bf16 x) { return __bfloat162float(x); }
__device__ __forceinline__ float toF(const float x) { return x; }

// load 8 consecutive elements as bf16x8 (converting if fp32)
__device__ __forceinline__ bf16x8 ld8(const float* p) {
  const float4 a0 = *(const float4*)p;
  const float4 a1 = *(const float4*)(p + 4);
  bf16x8 r;
  r[0] = (short)f2b(a0.x); r[1] = (short)f2b(a0.y);
  r[2] = (short)f2b(a0.z); r[3] = (short)f2b(a0.w);
  r[4] = (short)f2b(a1.x); r[5] = (short)f2b(a1.y);
  r[6] = (short)f2b(a1.z); r[7] = (short)f2b(a1.w);
  return r;
}
__device__ __forceinline__ bf16x8 ld8(const bf16* p) {
  return *(const bf16x8*)p;
}
__device__ __forceinline__ void storeC(float* p, float v) { *p = v; }
__device__ __forceinline__ void storeC(bf16* p, float v) {
  *p = __float2bfloat16(v);
}

// ---------------------------------------------------------------------------
// MFMA GEMM: C[M,64-col tile] (+)= A[M,K] @ W[K,N] + bias (ReLU optional).
// Grid (Nview/64, M/64, NZ); blockIdx.z selects (W,bias,C) set (QKV fusion).
// A row-major (lda=K), W row-major fp32 (ldw), C row-major (ldc).
// mfma_f32_16x16x32_bf16 layouts (verified round 4):
//   A: a[j]=A[m=lane&15][k=quad*8+j]  B: b[j]=B[k=quad*8+j][n=lane&15]
//   C/D: d[r]=D[row=quad*4+r][col=lane&15]
// ---------------------------------------------------------------------------
template <typename AT, typename CT, bool RELU, bool ACCUM>
__global__ __launch_bounds__(256) void gemm_mfma_kernel(
    const AT* __restrict__ A,
    const float* __restrict__ W0, const float* __restrict__ W1,
    const float* __restrict__ W2,
    const float* __restrict__ b0, const float* __restrict__ b1,
    const float* __restrict__ b2,
    CT* __restrict__ C0, CT* __restrict__ C1, CT* __restrict__ C2,
    int K, int ldw, int ldc) {
  const float* W = (blockIdx.z == 0) ? W0 : (blockIdx.z == 1 ? W1 : W2);
  const float* bias = (blockIdx.z == 0) ? b0 : (blockIdx.z == 1 ? b1 : b2);
  CT* C = (blockIdx.z == 0) ? C0 : (blockIdx.z == 1 ? C1 : C2);

  __shared__ short as[64][40];  // A tile [row][k], 80B rows
  __shared__ short bs[64][40];  // W tile transposed [n][k]

  const int rowBase = blockIdx.y * 64;
  const int colBase = blockIdx.x * 64;
  const int t = threadIdx.x;
  const int wave = t >> 6;
  const int lane = t & 63;
  const int quad = lane >> 4;
  const int l15 = lane & 15;

  // staging indices
  const int arow = t >> 2;          // 0..63
  const int akc = (t & 3) * 8;      // 0,8,16,24
  const int bn = t & 63;            // 0..63 (coalesced over lanes)
  const int bkg = (t >> 6) * 8;     // 0,8,16,24

  f32x4 acc[4];
#pragma unroll
  for (int nt = 0; nt < 4; ++nt) acc[nt] = (f32x4){0.f, 0.f, 0.f, 0.f};

  for (int k0 = 0; k0 < K; k0 += 32) {
    // stage A (64x32)
    *(bf16x8*)&as[arow][akc] =
        ld8(&A[(size_t)(rowBase + arow) * K + k0 + akc]);
    // stage W transposed (64n x 32k): 8 coalesced row-reads, packed b128 write
    {
      bf16x8 wv;
      const float* wp = &W[(size_t)(k0 + bkg) * ldw + colBase + bn];
#pragma unroll
      for (int j = 0; j < 8; ++j) wv[j] = (short)f2b(wp[(size_t)j * ldw]);
      *(bf16x8*)&bs[bn][bkg] = wv;
    }
    __syncthreads();

    const bf16x8 af = *(const bf16x8*)&as[wave * 16 + l15][quad * 8];
#pragma unroll
    for (int nt = 0; nt < 4; ++nt) {
      const bf16x8 bfr = *(const bf16x8*)&bs[nt * 16 + l15][quad * 8];
      acc[nt] = __builtin_amdgcn_mfma_f32_16x16x32_bf16(af, bfr, acc[nt], 0, 0, 0);
    }
    __syncthreads();
  }

  // epilogue
#pragma unroll
  for (int nt = 0; nt < 4; ++nt) {
    const int col = colBase + nt * 16 + l15;
#pragma unroll
    for (int r = 0; r < 4; ++r) {
      const int row = rowBase + wave * 16 + quad * 4 + r;
      float v = acc[nt][r];
      if (!ACCUM) v += bias[col];
      if (RELU) v = fmaxf(v, 0.f);
      CT* cp = &C[(size_t)row * ldc + col];
      if (ACCUM) v += toF(*cp);
      storeC(cp, v);
    }
  }
}

// ---------------------------------------------------------------------------
// MFMA flash attention (unchanged round 4). grid (SEQ/64, B*H), block 256.
// ---------------------------------------------------------------------------
__global__ __launch_bounds__(256) void attn_mfma_kernel(
    const bf16* __restrict__ Q, const bf16* __restrict__ Km,
    const bf16* __restrict__ V, const int* __restrict__ mask,
    bf16* __restrict__ ctx) {
  const int qt = blockIdx.x;
  const int bh = blockIdx.y;
  const int b = bh >> 3;
  const int h = bh & 7;
  const int t = threadIdx.x;
  const int wave = t >> 6;
  const int lane = t & 63;
  const int quad = lane >> 4;
  const int l15 = lane & 15;

  __shared__ short ks[64][72];
  __shared__ short vt[64][72];
  __shared__ float st[4][16][68];
  __shared__ int mk[64];

  bf16x8 qf[2];
  {
    const short* qg = (const short*)Q +
        (size_t)(b * SEQ + qt * 64 + wave * 16 + l15) * D_MODEL + h * D_K + quad * 8;
    qf[0] = *(const bf16x8*)qg;
    qf[1] = *(const bf16x8*)(qg + 32);
  }

  f32x4 of[4];
#pragma unroll
  for (int nt = 0; nt < 4; ++nt) of[nt] = (f32x4){0.f, 0.f, 0.f, 0.f};
  float m_run[4] = {-1e30f, -1e30f, -1e30f, -1e30f};
  float l_run[4] = {0.f, 0.f, 0.f, 0.f};

  const int kr = t >> 2, kc0 = (t & 3) * 16;
  const int vk = t & 63, vc0 = (t >> 6) * 16;

  for (int kt = 0; kt < SEQ / 64; ++kt) {
    {
      const short* kg = (const short*)Km +
          (size_t)(b * SEQ + kt * 64 + kr) * D_MODEL + h * D_K + kc0;
      *(bf16x8*)&ks[kr][kc0] = *(const bf16x8*)kg;
      *(bf16x8*)&ks[kr][kc0 + 8] = *(const bf16x8*)(kg + 8);
      const short* vg = (const short*)V +
          (size_t)(b * SEQ + kt * 64 + vk) * D_MODEL + h * D_K + vc0;
      bf16x8 v0 = *(const bf16x8*)vg;
      bf16x8 v1 = *(const bf16x8*)(vg + 8);
#pragma unroll
      for (int i = 0; i < 8; ++i) vt[vc0 + i][vk] = v0[i];
#pragma unroll
      for (int i = 0; i < 8; ++i) vt[vc0 + 8 + i][vk] = v1[i];
      if (t < 64) mk[t] = mask[b * SEQ + kt * 64 + t];
    }
    __syncthreads();

    f32x4 sf[4];
#pragma unroll
    for (int nt = 0; nt < 4; ++nt) {
      f32x4 acc = (f32x4){0.f, 0.f, 0.f, 0.f};
      bf16x8 kf0 = *(const bf16x8*)&ks[l15 + 16 * nt][quad * 8];
      bf16x8 kf1 = *(const bf16x8*)&ks[l15 + 16 * nt][quad * 8 + 32];
      acc = __builtin_amdgcn_mfma_f32_16x16x32_bf16(qf[0], kf0, acc, 0, 0, 0);
      acc = __builtin_amdgcn_mfma_f32_16x16x32_bf16(qf[1], kf1, acc, 0, 0, 0);
      sf[nt] = acc;
    }

    float mnew[4];
#pragma unroll
    for (int r = 0; r < 4; ++r) mnew[r] = m_run[r];
#pragma unroll
    for (int nt = 0; nt < 4; ++nt) {
      const bool dead = (mk[l15 + 16 * nt] == 0);
#pragma unroll
      for (int r = 0; r < 4; ++r) {
        float s = sf[nt][r] * 0.125f;
        if (dead) s = -1e9f;
        sf[nt][r] = s;
        mnew[r] = fmaxf(mnew[r], s);
      }
    }
#pragma unroll
    for (int xm = 1; xm < 16; xm <<= 1)
#pragma unroll
      for (int r = 0; r < 4; ++r)
        mnew[r] = fmaxf(mnew[r], __shfl_xor(mnew[r], xm, 64));

    float lsum[4] = {0.f, 0.f, 0.f, 0.f};
#pragma unroll
    for (int nt = 0; nt < 4; ++nt)
#pragma unroll
      for (int r = 0; r < 4; ++r) {
        float p = __expf(sf[nt][r] - mnew[r]);
        sf[nt][r] = p;
        lsum[r] += p;
      }
#pragma unroll
    for (int xm = 1; xm < 16; xm <<= 1)
#pragma unroll
      for (int r = 0; r < 4; ++r) lsum[r] += __shfl_xor(lsum[r], xm, 64);

#pragma unroll
    for (int r = 0; r < 4; ++r) {
      const float alpha = __expf(m_run[r] - mnew[r]);
      l_run[r] = l_run[r] * alpha + lsum[r];
      m_run[r] = mnew[r];
#pragma unroll
      for (int nt = 0; nt < 4; ++nt) of[nt][r] *= alpha;
    }

#pragma unroll
    for (int nt = 0; nt < 4; ++nt)
#pragma unroll
      for (int r = 0; r < 4; ++r)
        st[wave][quad * 4 + r][l15 + 16 * nt] = sf[nt][r];

#pragma unroll
    for (int kc = 0; kc < 2; ++kc) {
      float4 p0 = *(const float4*)&st[wave][l15][kc * 32 + quad * 8];
      float4 p1 = *(const float4*)&st[wave][l15][kc * 32 + quad * 8 + 4];
      bf16x8 pf;
      pf[0] = (short)f2b(p0.x); pf[1] = (short)f2b(p0.y);
      pf[2] = (short)f2b(p0.z); pf[3] = (short)f2b(p0.w);
      pf[4] = (short)f2b(p1.x); pf[5] = (short)f2b(p1.y);
      pf[6] = (short)f2b(p1.z); pf[7] = (short)f2b(p1.w);
#pragma unroll
      for (int nt = 0; nt < 4; ++nt) {
        bf16x8 vf = *(const bf16x8*)&vt[l15 + 16 * nt][kc * 32 + quad * 8];
        of[nt] = __builtin_amdgcn_mfma_f32_16x16x32_bf16(pf, vf, of[nt], 0, 0, 0);
      }
    }
    __syncthreads();
  }

#pragma unroll
  for (int r = 0; r < 4; ++r) {
    const float inv_l = 1.f / l_run[r];
    const int row = qt * 64 + wave * 16 + quad * 4 + r;
    bf16* cp = ctx + (size_t)(b * SEQ + row) * D_MODEL + h * D_K;
#pragma unroll
    for (int nt = 0; nt < 4; ++nt)
      cp[l15 + 16 * nt] = __float2bfloat16(of[nt][r] * inv_l);
  }
}

// ---------------------------------------------------------------------------
// Fused residual + LayerNorm over rows of 512. grid = NROWS, block = 256.
// ---------------------------------------------------------------------------
template <typename BT, typename RT, typename OT>
__global__ __launch_bounds__(256) void ln_kernel(
    const BT* __restrict__ base, const RT* __restrict__ res,
    const float* __restrict__ g, const float* __restrict__ beta,
    OT* __restrict__ out) {
  const int r = blockIdx.x;
  const int t = threadIdx.x;
  __shared__ float sred[256];

  const size_t rb = (size_t)r * D_MODEL;
  float v0 = toF(base[rb + t]) + toF(res[rb + t]);
  float v1 = toF(base[rb + t + 256]) + toF(res[rb + t + 256]);

  sred[t] = v0 + v1;
  __syncthreads();
#pragma unroll
  for (int s2 = 128; s2 > 0; s2 >>= 1) {
    if (t < s2) sred[t] += sred[t + s2];
    __syncthreads();
  }
  const float mu = sred[0] * (1.f / (float)D_MODEL);
  __syncthreads();

  const float d0 = v0 - mu;
  const float d1 = v1 - mu;
  sred[t] = d0 * d0 + d1 * d1;
  __syncthreads();
#pragma unroll
  for (int s2 = 128; s2 > 0; s2 >>= 1) {
    if (t < s2) sred[t] += sred[t + s2];
    __syncthreads();
  }
  const float var = sred[0] * (1.f / (float)D_MODEL);
  const float rs = rsqrtf(var + 1e-5f);

  storeC(&out[rb + t], d0 * rs * g[t] + beta[t]);
  storeC(&out[rb + t + 256], d1 * rs * g[t + 256] + beta[t + 256]);
}

// ---------------------------------------------------------------------------
extern "C" void kernel_launch(void* const* d_in, const int* in_sizes, int n_in,
                              void* d_out, int out_size, void* d_ws, size_t ws_size,
                              hipStream_t stream) {
  const float* x     = (const float*)d_in[0];
  const int*   mask  = (const int*)d_in[1];
  const float* Wq    = (const float*)d_in[2];
  const float* bq    = (const float*)d_in[3];
  const float* Wk    = (const float*)d_in[4];
  const float* bk    = (const float*)d_in[5];
  const float* Wv    = (const float*)d_in[6];
  const float* bv    = (const float*)d_in[7];
  const float* Wo    = (const float*)d_in[8];
  const float* bo    = (const float*)d_in[9];
  const float* W1    = (const float*)d_in[10];
  const float* b1    = (const float*)d_in[11];
  const float* W2    = (const float*)d_in[12];
  const float* b2    = (const float*)d_in[13];
  const float* g1    = (const float*)d_in[14];
  const float* beta1 = (const float*)d_in[15];
  const float* g2    = (const float*)d_in[16];
  const float* beta2 = (const float*)d_in[17];
  float* out = (float*)d_out;

  char* ws = (char*)d_ws;
  const size_t MB4 = (size_t)NROWS * D_MODEL * sizeof(bf16);  // 4 MiB
  bf16* q        = (bf16*)(ws + 0 * MB4);
  bf16* kbuf     = (bf16*)(ws + 1 * MB4);
  bf16* vbuf     = (bf16*)(ws + 2 * MB4);
  bf16* ctx      = (bf16*)(ws + 3 * MB4);
  bf16* attn_out = q;                      // q dead after attention
  bf16* x1       = (bf16*)(ws + 1 * MB4);  // k dead after attention
  bf16* ffmid    = (bf16*)(ws + 2 * MB4);  // [8,16): v,ctx dead after Wo
  bf16* ffacc    = (bf16*)(ws + 4 * MB4);  // [16,20)

  const dim3 blk(256);

  // QKV fused: grid z picks (W, bias, out)
  gemm_mfma_kernel<float, bf16, false, false>
      <<<dim3(D_MODEL / 64, NROWS / 64, 3), blk, 0, stream>>>(
          x, Wq, Wk, Wv, bq, bk, bv, q, kbuf, vbuf,
          D_MODEL, D_MODEL, D_MODEL);

  attn_mfma_kernel<<<dim3(SEQ / 64, BATCH * N_HEADS), blk, 0, stream>>>(
      q, kbuf, vbuf, mask, ctx);

  // Wo projection
  gemm_mfma_kernel<bf16, bf16, false, false>
      <<<dim3(D_MODEL / 64, NROWS / 64, 1), blk, 0, stream>>>(
          ctx, Wo, Wo, Wo, bo, bo, bo, attn_out, attn_out, attn_out,
          D_MODEL, D_MODEL, D_MODEL);

  // LN1: x1 = LN(x + attn_out) -> bf16
  ln_kernel<float, bf16, bf16><<<NROWS, blk, 0, stream>>>(
      x, attn_out, g1, beta1, x1);

  // FFN in 2 chunks of 1024
  for (int c = 0; c < 2; ++c) {
    gemm_mfma_kernel<bf16, bf16, true, false>
        <<<dim3(1024 / 64, NROWS / 64, 1), blk, 0, stream>>>(
            x1, W1 + c * 1024, W1 + c * 1024, W1 + c * 1024,
            b1 + c * 1024, b1 + c * 1024, b1 + c * 1024,
            ffmid, ffmid, ffmid, D_MODEL, D_FF, 1024);
    if (c == 0)
      gemm_mfma_kernel<bf16, bf16, false, false>
          <<<dim3(D_MODEL / 64, NROWS / 64, 1), blk, 0, stream>>>(
              ffmid, W2, W2, W2, b2, b2, b2, ffacc, ffacc, ffacc,
              1024, D_MODEL, D_MODEL);
    else
      gemm_mfma_kernel<bf16, bf16, false, true>
          <<<dim3(D_MODEL / 64, NROWS / 64, 1), blk, 0, stream>>>(
              ffmid, W2 + (size_t)1024 * D_MODEL, W2 + (size_t)1024 * D_MODEL,
              W2 + (size_t)1024 * D_MODEL, b2, b2, b2, ffacc, ffacc, ffacc,
              1024, D_MODEL, D_MODEL);
  }

  // LN2 -> fp32 output
  ln_kernel<bf16, bf16, float><<<NROWS, blk, 0, stream>>>(
      x1, ffacc, g2, beta2, out);
}